// Round 7
// baseline (686.403 us; speedup 1.0000x reference)
//
#include <hip/hip_runtime.h>
#include <hip/hip_fp16.h>
#include <cstdint>
#include <cstddef>

#define BN_EPS 1e-5f
#define KB 1024       // edge-chunk blocks for coarse hist / scatter
#define BSH 9         // 512 nodes per coarse bucket; requires N <= 131072

typedef _Float16 half8 __attribute__((ext_vector_type(8)));
typedef float floatx4 __attribute__((ext_vector_type(4)));

// ---------------------------------------------------------------------------
// fp16 helpers
// ---------------------------------------------------------------------------
__device__ __forceinline__ float loadS(const __half* p) { return __half2float(*p); }
__device__ __forceinline__ float2 load2(const __half* p) {
    return __half22float2(*(const __half2*)p);
}
__device__ __forceinline__ void storeS(float* p, float v) { *p = v; }
__device__ __forceinline__ void storeS(__half* p, float v) { *p = __float2half(v); }
__device__ __forceinline__ void store2(float* p, float a, float b) {
    *(float2*)p = make_float2(a, b);
}
__device__ __forceinline__ void store2(__half* p, float a, float b) {
    *(__half2*)p = __floats2half2_rn(a, b);
}
// packed edge word: (src << 15) | fp16 bits of (ew * dinv[dst]), sign stripped.
// word 0 => src 0, weight 0 (safe padding).
__device__ __forceinline__ float wn_of(unsigned v) {
    __half_raw hr; hr.x = (unsigned short)(v & 0x7fffu);
    return __half2float((__half)hr);
}

static __device__ __forceinline__ int load_edge(const void* ei, int mode64, long long pos) {
    if (mode64) return (int)((const long long*)ei)[pos];
    return ((const int*)ei)[pos];
}

// int64-vs-int32 edge_index detection, per wave (no cross-kernel dependency):
// sample the odd 4B words of the first 16 KB; all-zero => int64 high words.
__device__ __forceinline__ int detect_mode64(const unsigned* eiw) {
    const int lane = (int)threadIdx.x & 63;
    unsigned m = 0;
    for (int i = lane; i < 2048; i += 64) m |= eiw[2 * i + 1];
    return (__ballot(m != 0) == 0ULL) ? 1 : 0;
}

// ---------------------------------------------------------------------------
// K1: [0,160) W->WT fp16 transposes (+block 0 zeroes tickets) |
//     [160,160+KB) coarse histogram (LDS atomics, self-detected mode).
// ---------------------------------------------------------------------------
__global__ __launch_bounds__(256) void init_hist_kernel(const void* __restrict__ ei,
                                                        unsigned* __restrict__ tk,
                                                        unsigned* __restrict__ pc, int E, int epb,
                                                        const float* __restrict__ W1,
                                                        const float* __restrict__ W2,
                                                        const float* __restrict__ W3,
                                                        _Float16* __restrict__ WT1,
                                                        _Float16* __restrict__ WT2,
                                                        _Float16* __restrict__ WT3) {
    const int bid = (int)blockIdx.x;
    const int tid = (int)threadIdx.x;
    if (bid < 160) {
        if (bid == 0 && tid < 8) tk[tid] = 0u;
        const int t_ = bid;
        if (t_ < 64) {
            int t = t_ * 256 + tid;            // 128x128
            int n = t / 128, k = t % 128;
            WT1[t] = (_Float16)W1[k * 128 + n];
        } else if (t_ < 128) {
            int t = (t_ - 64) * 256 + tid;
            int n = t / 128, k = t % 128;
            WT2[t] = (_Float16)W2[k * 128 + n];
        } else {
            int t = (t_ - 128) * 256 + tid;    // 128x64
            int n = t / 128, k = t % 128;
            WT3[t] = (_Float16)W3[k * 64 + n];
        }
        return;
    }
    __shared__ unsigned h[256];
    const int k = bid - 160;
    h[tid] = 0;
    __syncthreads();
    const int md = detect_mode64((const unsigned*)ei);
    const int e0 = k * epb;
    const int e1 = min(E, e0 + epb);
    for (int e = e0 + tid; e < e1; e += 256) {
        int d = load_edge(ei, md, (long long)E + e);
        atomicAdd(&h[d >> BSH], 1u);
    }
    __syncthreads();
    pc[k * 256 + tid] = h[tid];
}

// ---------------------------------------------------------------------------
// K2: per-bucket exclusive scan over the KB chunk-blocks (in-place on pc,
// 4 chunks/thread), bucket totals -> tb. The LAST finishing block (ticket)
// additionally scans tb -> bbase and zeroes BN stats for layer 1.
// ---------------------------------------------------------------------------
__global__ __launch_bounds__(256) void scan_pc_kernel(unsigned* __restrict__ pc,
                                                      int* __restrict__ tb,
                                                      int* __restrict__ bbase,
                                                      float* __restrict__ gsum,
                                                      float* __restrict__ gsq,
                                                      unsigned* __restrict__ tk, int nbuck) {
    __shared__ int red[256];
    __shared__ int lastFlag;
    const int b = (int)blockIdx.x;
    const int tid = (int)threadIdx.x;
    unsigned v[4];
    int vals[4];
    int s = 0;
#pragma unroll
    for (int j = 0; j < 4; ++j) {
        v[j] = pc[(tid * 4 + j) * 256 + b];
        vals[j] = s;
        s += (int)v[j];
    }
    red[tid] = s;
    __syncthreads();
    for (int off = 1; off < 256; off <<= 1) {
        int t = 0;
        if (tid >= off) t = red[tid - off];
        __syncthreads();
        red[tid] += t;
        __syncthreads();
    }
    const int excl = red[tid] - s;
#pragma unroll
    for (int j = 0; j < 4; ++j)
        pc[(tid * 4 + j) * 256 + b] = (unsigned)(excl + vals[j]);
    if (tid == 255)
        __hip_atomic_store(&tb[b], red[255], __ATOMIC_RELEASE, __HIP_MEMORY_SCOPE_AGENT);
    __syncthreads();
    if (tid == 0) {
        unsigned t = __hip_atomic_fetch_add(tk, 1u, __ATOMIC_ACQ_REL, __HIP_MEMORY_SCOPE_AGENT);
        lastFlag = (t == (unsigned)gridDim.x - 1u) ? 1 : 0;
    }
    __syncthreads();
    if (!lastFlag) return;
    // last block: scan bucket totals -> bbase
    const int v2 = (tid < nbuck)
        ? __hip_atomic_load(&tb[tid], __ATOMIC_ACQUIRE, __HIP_MEMORY_SCOPE_AGENT) : 0;
    __syncthreads();
    red[tid] = v2;
    __syncthreads();
    for (int off = 1; off < 256; off <<= 1) {
        int t = 0;
        if (tid >= off) t = red[tid - off];
        __syncthreads();
        red[tid] += t;
        __syncthreads();
    }
    bbase[tid] = red[tid] - v2;
    if (tid < 128) { gsum[tid] = 0.0f; gsq[tid] = 0.0f; }
}

// ---------------------------------------------------------------------------
// MFMA GEMM body. v_mfma_f32_16x16x32_f16, 4 waves, 64 rows/block.
// W pre-transposed fp16 [M][128] in global, staged to LDS.
// ---------------------------------------------------------------------------
template <int M, bool BN, typename TI>
__device__ __forceinline__ void gemm_body(int gbid, const TI* __restrict__ X,
                                          const _Float16* __restrict__ WTg,
                                          const float* __restrict__ sc,
                                          const float* __restrict__ sh,
                                          __half* __restrict__ Hout, int N,
                                          _Float16* WT /* LDS, M*136 */) {
    constexpr int CT = M / 16;
    constexpr int LDK = 136;

    for (int t = threadIdx.x; t < M * 16; t += 256) {
        int n = t / 16, seg = t % 16;
        *(half8*)&WT[n * LDK + seg * 8] = *(const half8*)&WTg[n * 128 + seg * 8];
    }
    __syncthreads();

    const int wave = (int)threadIdx.x >> 6;
    const int lane = (int)threadIdx.x & 63;
    const int qd = lane >> 4;
    const int ln = lane & 15;
    const int tile0 = gbid * 64 + wave * 16;
    int ar = tile0 + ln;
    if (ar >= N) ar = N - 1;  // clamp (stores guarded)

    half8 aF[4];
    const TI* xr = X + (size_t)ar * 128 + qd * 8;
#pragma unroll
    for (int kb = 0; kb < 4; ++kb) {
        float vv[8];
        if constexpr (sizeof(TI) == 4) {
            float4 v0 = *(const float4*)(xr + kb * 32);
            float4 v1 = *(const float4*)(xr + kb * 32 + 4);
            vv[0] = v0.x; vv[1] = v0.y; vv[2] = v0.z; vv[3] = v0.w;
            vv[4] = v1.x; vv[5] = v1.y; vv[6] = v1.z; vv[7] = v1.w;
        } else {
            half8 raw = *(const half8*)(xr + kb * 32);
#pragma unroll
            for (int j = 0; j < 8; ++j) vv[j] = (float)raw[j];
        }
        if (BN) {
            const int kbase = kb * 32 + qd * 8;
#pragma unroll
            for (int j = 0; j < 8; ++j)
                vv[j] = fmaxf(fmaf(vv[j], sc[kbase + j], sh[kbase + j]), 0.0f);
        }
        half8 a;
#pragma unroll
        for (int j = 0; j < 8; ++j) a[j] = (_Float16)vv[j];
        aF[kb] = a;
    }

#pragma unroll
    for (int ct = 0; ct < CT; ++ct) {
        floatx4 acc = {0.0f, 0.0f, 0.0f, 0.0f};
#pragma unroll
        for (int kb = 0; kb < 4; ++kb) {
            half8 b = *(const half8*)&WT[(ct * 16 + ln) * LDK + kb * 32 + qd * 8];
            acc = __builtin_amdgcn_mfma_f32_16x16x32_f16(aF[kb], b, acc, 0, 0, 0);
        }
#pragma unroll
        for (int r = 0; r < 4; ++r) {
            int orow = tile0 + qd * 4 + r;
            if (orow < N) Hout[(size_t)orow * M + ct * 16 + ln] = __float2half(acc[r]);
        }
    }
}

// ---------------------------------------------------------------------------
// K3: [0,KB) = bucket scatter (FIRST, so it overlaps the GEMM);
// [KB,KB+GB) = GEMM1 (x@W1 -> H). Scatter replays the coarse histogram with
// LDS atomics; payload u64 = d:17 | src:17 | ew_fp16. No global atomics.
// ---------------------------------------------------------------------------
__global__ __launch_bounds__(256) void sort_gemm1_kernel(const void* __restrict__ ei,
                                                         const float* __restrict__ ew,
                                                         const unsigned* __restrict__ pc,
                                                         const int* __restrict__ bbase,
                                                         unsigned long long* __restrict__ sortedE,
                                                         int E, int epb,
                                                         const float* __restrict__ X,
                                                         const _Float16* __restrict__ WT1g,
                                                         __half* __restrict__ Hout, int N) {
    __shared__ _Float16 WT[128 * 136];
    __shared__ unsigned off_s[256];
    if ((int)blockIdx.x >= KB) {
        gemm_body<128, false, float>((int)blockIdx.x - KB, X, WT1g, nullptr, nullptr,
                                     Hout, N, WT);
        return;
    }
    const int k = (int)blockIdx.x;
    const int tid = (int)threadIdx.x;
    off_s[tid] = (unsigned)bbase[tid] + pc[k * 256 + tid];
    __syncthreads();
    const int md = detect_mode64((const unsigned*)ei);
    const int e0 = k * epb;
    const int e1 = min(E, e0 + epb);
    for (int e = e0 + tid; e < e1; e += 256) {
        int d = load_edge(ei, md, (long long)E + e);
        int s = load_edge(ei, md, e);
        float wv = ew[e];
        unsigned slot = atomicAdd(&off_s[d >> BSH], 1u);
        sortedE[slot] = ((unsigned long long)(unsigned)d << 33) |
                        ((unsigned long long)(unsigned)s << 16) |
                        (unsigned long long)(unsigned short)__half_as_ushort(__float2half(wv));
    }
}

// ---------------------------------------------------------------------------
// K4: per-bucket CSR build. Bucket = 512 consecutive nodes; its edges are a
// contiguous run of sortedE. LDS: fine counts + fp32 weight sums (pass 1),
// LDS scan -> cnt/dinv/row_start, pass 2 writes edata (unique rank via LDS
// atomic; order-unstable, sum-commutative => valid).
// ---------------------------------------------------------------------------
__global__ __launch_bounds__(256) void csr_build_kernel(const unsigned long long* __restrict__ sortedE,
                                                        const int* __restrict__ bbase,
                                                        const int* __restrict__ tb,
                                                        float* __restrict__ dinv,
                                                        int* __restrict__ cnt,
                                                        int* __restrict__ row_start,
                                                        unsigned* __restrict__ edata, int N) {
    __shared__ unsigned cs[512];
    __shared__ float ws[512];
    __shared__ float dv[512];
    __shared__ unsigned sc[512];
    __shared__ unsigned cur[512];
    __shared__ int red[256];
    const int b = (int)blockIdx.x;
    const int tid = (int)threadIdx.x;
    const int n0 = b << BSH;
    const int base = bbase[b];
    const int len = tb[b];

    cs[tid] = 0; cs[tid + 256] = 0;
    ws[tid] = 0.0f; ws[tid + 256] = 0.0f;
    cur[tid] = 0; cur[tid + 256] = 0;
    __syncthreads();

    for (int i = tid; i < len; i += 256) {
        unsigned long long p = sortedE[base + i];
        unsigned fine = (unsigned)(p >> 33) - (unsigned)n0;
        atomicAdd(&cs[fine], 1u);
        __half_raw hr; hr.x = (unsigned short)(p & 0xFFFFu);
        atomicAdd(&ws[fine], __half2float((__half)hr));
    }
    __syncthreads();

    // exclusive scan of cs over 512 bins (pair per thread)
    const unsigned a0 = cs[2 * tid];
    const unsigned a1 = cs[2 * tid + 1];
    const int s2 = (int)(a0 + a1);
    red[tid] = s2;
    __syncthreads();
    for (int off = 1; off < 256; off <<= 1) {
        int t = 0;
        if (tid >= off) t = red[tid - off];
        __syncthreads();
        red[tid] += t;
        __syncthreads();
    }
    const int excl2 = red[tid] - s2;
    sc[2 * tid] = (unsigned)excl2;
    sc[2 * tid + 1] = (unsigned)(excl2 + (int)a0);

#pragma unroll
    for (int q = 0; q < 2; ++q) {
        const int f = tid + q * 256;
        const int node = n0 + f;
        const float dvv = rsqrtf(1.0f + ws[f]);  // self-loop weight 1 included
        dv[f] = dvv;
        if (node < N) {
            dinv[node] = dvv;
            cnt[node] = (int)cs[f];
            row_start[node] = base + (int)sc[f];
        }
    }
    __syncthreads();

    for (int i = tid; i < len; i += 256) {
        unsigned long long p = sortedE[base + i];
        unsigned fine = (unsigned)(p >> 33) - (unsigned)n0;
        unsigned s = (unsigned)(p >> 16) & 0x1FFFFu;
        __half_raw hr; hr.x = (unsigned short)(p & 0xFFFFu);
        float wnp = __half2float((__half)hr) * dv[fine];  // ew * dinv[dst]
        unsigned r = atomicAdd(&cur[fine], 1u);
        unsigned hb = (unsigned)__half_as_ushort(__float2half(wnp)) & 0x7fffu;
        edata[base + (int)sc[fine] + (int)r] = (s << 15) | hb;
    }
}

// ---------------------------------------------------------------------------
// CSR aggregation v3: 16 nodes per block (4 per wave). Node metadata + the
// block's CONTIGUOUS edata slab staged in LDS (row_start is globally
// monotonic), then each wave runs a 16-deep gather pipeline per node — no
// ev-load/shfl serialization, 32 VMEM ops in flight, metadata amortized.
// ---------------------------------------------------------------------------
template <int D, bool BIAS, typename TY>
__global__ __launch_bounds__(256) void agg_kernel(const __half* __restrict__ H,
                                                  const unsigned* __restrict__ edata,
                                                  const int* __restrict__ row_start,
                                                  const int* __restrict__ cnt,
                                                  const float* __restrict__ dinv,
                                                  const float* __restrict__ bias,
                                                  TY* __restrict__ Y, int N) {
    constexpr int VPT = D / 64;  // 2 (D=128) or 1 (D=64)
    constexpr int NPB = 16;
    constexpr int CAP = 2048;
    __shared__ unsigned eb[CAP];
    __shared__ int rs_s[NPB], cn_s[NPB];
    __shared__ float dv_s[NPB];
    const int tid = (int)threadIdx.x;
    const int wave = tid >> 6;
    const int lane = tid & 63;
    const int i0 = (int)blockIdx.x * NPB;
    const int c0 = lane * VPT;

    if (tid < NPB) {
        int i = i0 + tid;
        int ii = (i < N) ? i : (N - 1);
        rs_s[tid] = row_start[ii];
        cn_s[tid] = (i < N) ? cnt[ii] : 0;
        dv_s[tid] = dinv[ii];
    }
    __syncthreads();
    const int base = rs_s[0];
    int total = 0;
#pragma unroll
    for (int k = 0; k < NPB; ++k) total = max(total, rs_s[k] + cn_s[k] - base);

    float a0[4], a1[4];
#pragma unroll
    for (int nn = 0; nn < 4; ++nn) {
        const int idx = wave * 4 + nn;
        const int i = i0 + idx;
        a0[nn] = 0.0f; a1[nn] = 0.0f;
        if (i < N) {
            const float di = dv_s[idx];
            if constexpr (VPT == 2) {
                float2 h = load2(H + (size_t)i * D + c0);
                a0[nn] = di * di * h.x;
                a1[nn] = di * di * h.y;
            } else {
                a0[nn] = di * di * loadS(H + (size_t)i * D + c0);
            }
        }
    }

    for (int cb = 0; cb < total; cb += CAP) {
        const int clen = min(CAP, total - cb);
        __syncthreads();
        for (int e = tid; e < clen; e += 256) eb[e] = edata[base + cb + e];
        __syncthreads();
#pragma unroll
        for (int nn = 0; nn < 4; ++nn) {
            const int idx = wave * 4 + nn;
            const int i = i0 + idx;
            if (i >= N) continue;
            const int lo = rs_s[idx] - base;
            const int hi = lo + cn_s[idx];
            const int s = max(lo, cb);
            const int epos = min(hi, cb + clen);
            for (int j = s; j < epos; j += 16) {
                unsigned ev[16];
#pragma unroll
                for (int k = 0; k < 16; ++k)
                    ev[k] = (j + k < epos) ? eb[j + k - cb] : 0u;
                float wk[16];
#pragma unroll
                for (int k = 0; k < 16; ++k) wk[k] = dinv[ev[k] >> 15] * wn_of(ev[k]);
                if constexpr (VPT == 2) {
                    float2 hh[16];
#pragma unroll
                    for (int k = 0; k < 16; ++k)
                        hh[k] = load2(H + (size_t)(ev[k] >> 15) * D + c0);
#pragma unroll
                    for (int k = 0; k < 16; ++k) {
                        a0[nn] = fmaf(wk[k], hh[k].x, a0[nn]);
                        a1[nn] = fmaf(wk[k], hh[k].y, a1[nn]);
                    }
                } else {
                    float hh[16];
#pragma unroll
                    for (int k = 0; k < 16; ++k)
                        hh[k] = loadS(H + (size_t)(ev[k] >> 15) * D + c0);
#pragma unroll
                    for (int k = 0; k < 16; ++k)
                        a0[nn] = fmaf(wk[k], hh[k], a0[nn]);
                }
            }
        }
    }

#pragma unroll
    for (int nn = 0; nn < 4; ++nn) {
        const int idx = wave * 4 + nn;
        const int i = i0 + idx;
        if (i >= N) continue;
        float v0 = a0[nn], v1 = a1[nn];
        if constexpr (VPT == 2) {
            if (BIAS) { v0 += bias[c0]; v1 += bias[c0 + 1]; }
            store2(Y + (size_t)i * D + c0, v0, v1);
        } else {
            if (BIAS) v0 += bias[c0];
            storeS(Y + (size_t)i * D + c0, v0);
        }
    }
}

// ---------------------------------------------------------------------------
// GEMM dispatch wrapper; optional extra block zeroes next layer's BN stats.
// ---------------------------------------------------------------------------
template <int M, bool BN, typename TI, bool ZERO>
__global__ __launch_bounds__(256) void gemm_mfma_kernel(const TI* __restrict__ X,
                                                        const _Float16* __restrict__ WTg,
                                                        const float* __restrict__ sc,
                                                        const float* __restrict__ sh,
                                                        __half* __restrict__ Hout, int N,
                                                        float* __restrict__ gsum,
                                                        float* __restrict__ gsq, int GB) {
    __shared__ _Float16 WT[M * 136];
    if (ZERO && (int)blockIdx.x == GB) {
        if (threadIdx.x < 128) { gsum[threadIdx.x] = 0.0f; gsq[threadIdx.x] = 0.0f; }
        return;
    }
    gemm_body<M, BN, TI>(blockIdx.x, X, WTg, sc, sh, Hout, N, WT);
}

// ---------------------------------------------------------------------------
// BatchNorm statistics (fp16 Y) + fused finalize in the LAST block (ticket).
// ---------------------------------------------------------------------------
__global__ __launch_bounds__(256) void stats_kernel(const __half* __restrict__ Y,
                                                    float* __restrict__ gsum,
                                                    float* __restrict__ gsq,
                                                    unsigned* __restrict__ tk,
                                                    const float* __restrict__ gamma,
                                                    const float* __restrict__ beta,
                                                    float* __restrict__ sc,
                                                    float* __restrict__ sh, int N) {
    __shared__ float ls[256], lq[256];
    __shared__ int lastFlag;
    const int tid = (int)threadIdx.x;
    const int c = tid & 127;
    const int half_ = tid >> 7;
    float s = 0.0f, q = 0.0f;
    for (int row = (int)blockIdx.x * 2 + half_; row < N; row += 512) {
        float v = __half2float(Y[(size_t)row * 128 + c]);
        s += v;
        q = fmaf(v, v, q);
    }
    ls[tid] = s; lq[tid] = q;
    __syncthreads();
    if (tid < 128) {
        atomicAdd(&gsum[c], ls[tid] + ls[tid + 128]);
        atomicAdd(&gsq[c],  lq[tid] + lq[tid + 128]);
    }
    __syncthreads();
    if (tid == 0) {
        unsigned t = __hip_atomic_fetch_add(tk, 1u, __ATOMIC_ACQ_REL, __HIP_MEMORY_SCOPE_AGENT);
        lastFlag = (t == (unsigned)gridDim.x - 1u) ? 1 : 0;
    }
    __syncthreads();
    if (!lastFlag) return;
    if (tid < 128) {
        float gs = __hip_atomic_load(&gsum[tid], __ATOMIC_ACQUIRE, __HIP_MEMORY_SCOPE_AGENT);
        float gq = __hip_atomic_load(&gsq[tid], __ATOMIC_ACQUIRE, __HIP_MEMORY_SCOPE_AGENT);
        float inv_n = 1.0f / (float)N;
        float mean = gs * inv_n;
        float var = gq * inv_n - mean * mean;
        float scale = gamma[tid] * rsqrtf(var + BN_EPS);
        sc[tid] = scale;
        sh[tid] = beta[tid] - mean * scale;
    }
}

// ---------------------------------------------------------------------------
// Launch (11 kernels)
// ---------------------------------------------------------------------------
extern "C" void kernel_launch(void* const* d_in, const int* in_sizes, int n_in,
                              void* d_out, int out_size, void* d_ws, size_t ws_size,
                              hipStream_t stream) {
    const float* x   = (const float*)d_in[0];
    const void*  ei  = d_in[1];
    const float* ew  = (const float*)d_in[2];
    const float* W1  = (const float*)d_in[3];
    const float* W2  = (const float*)d_in[5];
    const float* W3  = (const float*)d_in[7];
    const float* b3  = (const float*)d_in[8];
    const float* g1  = (const float*)d_in[9];
    const float* be1 = (const float*)d_in[10];
    const float* g2  = (const float*)d_in[11];
    const float* be2 = (const float*)d_in[12];
    float* out = (float*)d_out;

    const int N = in_sizes[0] / 128;   // 100000 (payload packing needs N <= 2^17)
    const int E = in_sizes[2];

    char* w = (char*)d_ws;
    size_t off = 0;
    auto alloc = [&](size_t bytes) -> void* {
        void* p = w + off;
        off += (bytes + 255) & ~(size_t)255;
        return p;
    };
    unsigned* pc     = (unsigned*)alloc((size_t)KB * 256 * 4);
    int*   tb        = (int*)  alloc(256 * 4);
    int*   bbase     = (int*)  alloc(256 * 4);
    unsigned long long* sortedE = (unsigned long long*)alloc((size_t)E * 8);
    float* dinv      = (float*)alloc((size_t)N * 4);
    int*   cnt       = (int*)  alloc((size_t)N * 4);
    int*   row_start = (int*)  alloc((size_t)N * 4);
    unsigned* edata  = (unsigned*)alloc((size_t)E * 4);
    unsigned* tk     = (unsigned*)alloc(256);
    float* gsum      = (float*)alloc(128 * 4);
    float* gsq       = (float*)alloc(128 * 4);
    float* scb       = (float*)alloc(128 * 4);
    float* shb       = (float*)alloc(128 * 4);
    _Float16* WT1    = (_Float16*)alloc(128 * 128 * 2);
    _Float16* WT2    = (_Float16*)alloc(128 * 128 * 2);
    _Float16* WT3    = (_Float16*)alloc(128 * 64 * 2);
    __half* H        = (__half*)alloc((size_t)N * 128 * 2);  // gemm out / agg in
    __half* Yh       = (__half*)alloc((size_t)N * 128 * 2);  // agg out / next gemm in
    (void)ws_size; (void)n_in; (void)out_size;

    const int epb   = (E + KB - 1) / KB;            // edges per chunk block
    const int nbuck = (N + (1 << BSH) - 1) >> BSH;  // coarse buckets (<=256)
    const int gb    = (N + 63) / 64;
    const int ab    = (N + 15) / 16;                // agg v3: 16 nodes/block

    // K1: W transposes + tickets + coarse histogram (self-detected mode)
    init_hist_kernel<<<160 + KB, 256, 0, stream>>>(ei, tk, pc, E, epb,
                                                   W1, W2, W3, WT1, WT2, WT3);
    // K2: per-bucket scans (+ last block: bucket bases, zero BN stats L1)
    scan_pc_kernel<<<nbuck, 256, 0, stream>>>(pc, tb, bbase, gsum, gsq, &tk[0], nbuck);
    // K3: bucket scatter (first, overlaps) + GEMM1
    sort_gemm1_kernel<<<KB + gb, 256, 0, stream>>>(ei, ew, pc, bbase, sortedE, E,
                                                   epb, x, WT1, H, N);
    // K4: per-bucket CSR build -> cnt, dinv, row_start, edata
    csr_build_kernel<<<nbuck, 256, 0, stream>>>(sortedE, bbase, tb, dinv, cnt, row_start,
                                                edata, N);

    // ---- L1: Yh = Ahat*H ----
    agg_kernel<128, false, __half><<<ab, 256, 0, stream>>>(H, edata, row_start, cnt, dinv, nullptr, Yh, N);
    stats_kernel<<<256, 256, 0, stream>>>(Yh, gsum, gsq, &tk[1], g1, be1, scb, shb, N);

    // ---- L2: H = relu(bn(Yh))@W2 ; Yh = Ahat*H ----
    gemm_mfma_kernel<128, true, __half, true><<<gb + 1, 256, 0, stream>>>(
        Yh, WT2, scb, shb, H, N, gsum, gsq, gb);
    agg_kernel<128, false, __half><<<ab, 256, 0, stream>>>(H, edata, row_start, cnt, dinv, nullptr, Yh, N);
    stats_kernel<<<256, 256, 0, stream>>>(Yh, gsum, gsq, &tk[2], g2, be2, scb, shb, N);

    // ---- L3: H64 = relu(bn(Yh))@W3 ; out = Ahat*H64 + b3 ----
    gemm_mfma_kernel<64, true, __half, false><<<gb, 256, 0, stream>>>(
        Yh, WT3, scb, shb, H, N, nullptr, nullptr, gb);
    agg_kernel<64, true, float><<<ab, 256, 0, stream>>>(H, edata, row_start, cnt, dinv, b3, out, N);
}

// Round 9
// 497.086 us; speedup vs baseline: 1.3809x; 1.3809x over previous
//
#include <hip/hip_runtime.h>
#include <hip/hip_fp16.h>
#include <cstdint>
#include <cstddef>

#define BN_EPS 1e-5f
#define KB 1024       // edge-chunk blocks for coarse hist / scatter
#define BSH 9         // 512 nodes per coarse bucket; requires N <= 131072

typedef _Float16 half8 __attribute__((ext_vector_type(8)));
typedef float floatx4 __attribute__((ext_vector_type(4)));

// ---------------------------------------------------------------------------
// fp16 helpers
// ---------------------------------------------------------------------------
__device__ __forceinline__ float loadS(const __half* p) { return __half2float(*p); }
__device__ __forceinline__ float2 load2(const __half* p) {
    return __half22float2(*(const __half2*)p);
}
__device__ __forceinline__ void storeS(float* p, float v) { *p = v; }
__device__ __forceinline__ void storeS(__half* p, float v) { *p = __float2half(v); }
__device__ __forceinline__ void store2(float* p, float a, float b) {
    *(float2*)p = make_float2(a, b);
}
__device__ __forceinline__ void store2(__half* p, float a, float b) {
    *(__half2*)p = __floats2half2_rn(a, b);
}
// packed edge word: (src << 15) | fp16 bits of (ew * dinv[dst]), sign stripped.
// word 0 => src 0, weight 0 (safe padding).
__device__ __forceinline__ float wn_of(unsigned v) {
    __half_raw hr; hr.x = (unsigned short)(v & 0x7fffu);
    return __half2float((__half)hr);
}

static __device__ __forceinline__ int load_edge(const void* ei, int mode64, long long pos) {
    if (mode64) return (int)((const long long*)ei)[pos];
    return ((const int*)ei)[pos];
}

// int64-vs-int32 edge_index detection, per wave (no cross-kernel dependency):
// sample the odd 4B words of the first 16 KB; all-zero => int64 high words.
__device__ __forceinline__ int detect_mode64(const unsigned* eiw) {
    const int lane = (int)threadIdx.x & 63;
    unsigned m = 0;
    for (int i = lane; i < 2048; i += 64) m |= eiw[2 * i + 1];
    return (__ballot(m != 0) == 0ULL) ? 1 : 0;
}

// ---------------------------------------------------------------------------
// K1: [0,160) W->WT fp16 transposes (+block 0 zeroes tickets) |
//     [160,160+KB) coarse histogram (LDS atomics, self-detected mode).
// ---------------------------------------------------------------------------
__global__ __launch_bounds__(256) void init_hist_kernel(const void* __restrict__ ei,
                                                        unsigned* __restrict__ tk,
                                                        unsigned* __restrict__ pc, int E, int epb,
                                                        const float* __restrict__ W1,
                                                        const float* __restrict__ W2,
                                                        const float* __restrict__ W3,
                                                        _Float16* __restrict__ WT1,
                                                        _Float16* __restrict__ WT2,
                                                        _Float16* __restrict__ WT3) {
    const int bid = (int)blockIdx.x;
    const int tid = (int)threadIdx.x;
    if (bid < 160) {
        if (bid == 0 && tid < 8) tk[tid] = 0u;
        const int t_ = bid;
        if (t_ < 64) {
            int t = t_ * 256 + tid;            // 128x128
            int n = t / 128, k = t % 128;
            WT1[t] = (_Float16)W1[k * 128 + n];
        } else if (t_ < 128) {
            int t = (t_ - 64) * 256 + tid;
            int n = t / 128, k = t % 128;
            WT2[t] = (_Float16)W2[k * 128 + n];
        } else {
            int t = (t_ - 128) * 256 + tid;    // 128x64
            int n = t / 128, k = t % 128;
            WT3[t] = (_Float16)W3[k * 64 + n];
        }
        return;
    }
    __shared__ unsigned h[256];
    const int k = bid - 160;
    h[tid] = 0;
    __syncthreads();
    const int md = detect_mode64((const unsigned*)ei);
    const int e0 = k * epb;
    const int e1 = min(E, e0 + epb);
    for (int e = e0 + tid; e < e1; e += 256) {
        int d = load_edge(ei, md, (long long)E + e);
        atomicAdd(&h[d >> BSH], 1u);
    }
    __syncthreads();
    pc[k * 256 + tid] = h[tid];
}

// ---------------------------------------------------------------------------
// K2: per-bucket exclusive scan over the KB chunk-blocks (in-place on pc,
// 4 chunks/thread), bucket totals -> tb. The LAST finishing block (ticket)
// additionally scans tb -> bbase and zeroes BN stats for layer 1.
// ---------------------------------------------------------------------------
__global__ __launch_bounds__(256) void scan_pc_kernel(unsigned* __restrict__ pc,
                                                      int* __restrict__ tb,
                                                      int* __restrict__ bbase,
                                                      float* __restrict__ gsum,
                                                      float* __restrict__ gsq,
                                                      unsigned* __restrict__ tk, int nbuck) {
    __shared__ int red[256];
    __shared__ int lastFlag;
    const int b = (int)blockIdx.x;
    const int tid = (int)threadIdx.x;
    unsigned v[4];
    int vals[4];
    int s = 0;
#pragma unroll
    for (int j = 0; j < 4; ++j) {
        v[j] = pc[(tid * 4 + j) * 256 + b];
        vals[j] = s;
        s += (int)v[j];
    }
    red[tid] = s;
    __syncthreads();
    for (int off = 1; off < 256; off <<= 1) {
        int t = 0;
        if (tid >= off) t = red[tid - off];
        __syncthreads();
        red[tid] += t;
        __syncthreads();
    }
    const int excl = red[tid] - s;
#pragma unroll
    for (int j = 0; j < 4; ++j)
        pc[(tid * 4 + j) * 256 + b] = (unsigned)(excl + vals[j]);
    if (tid == 255)
        __hip_atomic_store(&tb[b], red[255], __ATOMIC_RELEASE, __HIP_MEMORY_SCOPE_AGENT);
    __syncthreads();
    if (tid == 0) {
        unsigned t = __hip_atomic_fetch_add(tk, 1u, __ATOMIC_ACQ_REL, __HIP_MEMORY_SCOPE_AGENT);
        lastFlag = (t == (unsigned)gridDim.x - 1u) ? 1 : 0;
    }
    __syncthreads();
    if (!lastFlag) return;
    // last block: scan bucket totals -> bbase
    const int v2 = (tid < nbuck)
        ? __hip_atomic_load(&tb[tid], __ATOMIC_ACQUIRE, __HIP_MEMORY_SCOPE_AGENT) : 0;
    __syncthreads();
    red[tid] = v2;
    __syncthreads();
    for (int off = 1; off < 256; off <<= 1) {
        int t = 0;
        if (tid >= off) t = red[tid - off];
        __syncthreads();
        red[tid] += t;
        __syncthreads();
    }
    bbase[tid] = red[tid] - v2;
    if (tid < 128) { gsum[tid] = 0.0f; gsq[tid] = 0.0f; }
}

// ---------------------------------------------------------------------------
// MFMA GEMM body. v_mfma_f32_16x16x32_f16, 4 waves, 64 rows/block.
// W pre-transposed fp16 [M][128] in global, staged to LDS.
// ---------------------------------------------------------------------------
template <int M, bool BN, typename TI>
__device__ __forceinline__ void gemm_body(int gbid, const TI* __restrict__ X,
                                          const _Float16* __restrict__ WTg,
                                          const float* __restrict__ sc,
                                          const float* __restrict__ sh,
                                          __half* __restrict__ Hout, int N,
                                          _Float16* WT /* LDS, M*136 */) {
    constexpr int CT = M / 16;
    constexpr int LDK = 136;

    for (int t = threadIdx.x; t < M * 16; t += 256) {
        int n = t / 16, seg = t % 16;
        *(half8*)&WT[n * LDK + seg * 8] = *(const half8*)&WTg[n * 128 + seg * 8];
    }
    __syncthreads();

    const int wave = (int)threadIdx.x >> 6;
    const int lane = (int)threadIdx.x & 63;
    const int qd = lane >> 4;
    const int ln = lane & 15;
    const int tile0 = gbid * 64 + wave * 16;
    int ar = tile0 + ln;
    if (ar >= N) ar = N - 1;  // clamp (stores guarded)

    half8 aF[4];
    const TI* xr = X + (size_t)ar * 128 + qd * 8;
#pragma unroll
    for (int kb = 0; kb < 4; ++kb) {
        float vv[8];
        if constexpr (sizeof(TI) == 4) {
            float4 v0 = *(const float4*)(xr + kb * 32);
            float4 v1 = *(const float4*)(xr + kb * 32 + 4);
            vv[0] = v0.x; vv[1] = v0.y; vv[2] = v0.z; vv[3] = v0.w;
            vv[4] = v1.x; vv[5] = v1.y; vv[6] = v1.z; vv[7] = v1.w;
        } else {
            half8 raw = *(const half8*)(xr + kb * 32);
#pragma unroll
            for (int j = 0; j < 8; ++j) vv[j] = (float)raw[j];
        }
        if (BN) {
            const int kbase = kb * 32 + qd * 8;
#pragma unroll
            for (int j = 0; j < 8; ++j)
                vv[j] = fmaxf(fmaf(vv[j], sc[kbase + j], sh[kbase + j]), 0.0f);
        }
        half8 a;
#pragma unroll
        for (int j = 0; j < 8; ++j) a[j] = (_Float16)vv[j];
        aF[kb] = a;
    }

#pragma unroll
    for (int ct = 0; ct < CT; ++ct) {
        floatx4 acc = {0.0f, 0.0f, 0.0f, 0.0f};
#pragma unroll
        for (int kb = 0; kb < 4; ++kb) {
            half8 b = *(const half8*)&WT[(ct * 16 + ln) * LDK + kb * 32 + qd * 8];
            acc = __builtin_amdgcn_mfma_f32_16x16x32_f16(aF[kb], b, acc, 0, 0, 0);
        }
#pragma unroll
        for (int r = 0; r < 4; ++r) {
            int orow = tile0 + qd * 4 + r;
            if (orow < N) Hout[(size_t)orow * M + ct * 16 + ln] = __float2half(acc[r]);
        }
    }
}

// ---------------------------------------------------------------------------
// K3: [0,KB) = bucket scatter (FIRST, so it overlaps the GEMM);
// [KB,KB+GB) = GEMM1 (x@W1 -> H). Scatter replays the coarse histogram with
// LDS atomics; payload u64 = d:17 | src:17 | ew_fp16. No global atomics.
// ---------------------------------------------------------------------------
__global__ __launch_bounds__(256) void sort_gemm1_kernel(const void* __restrict__ ei,
                                                         const float* __restrict__ ew,
                                                         const unsigned* __restrict__ pc,
                                                         const int* __restrict__ bbase,
                                                         unsigned long long* __restrict__ sortedE,
                                                         int E, int epb,
                                                         const float* __restrict__ X,
                                                         const _Float16* __restrict__ WT1g,
                                                         __half* __restrict__ Hout, int N) {
    __shared__ _Float16 WT[128 * 136];
    __shared__ unsigned off_s[256];
    if ((int)blockIdx.x >= KB) {
        gemm_body<128, false, float>((int)blockIdx.x - KB, X, WT1g, nullptr, nullptr,
                                     Hout, N, WT);
        return;
    }
    const int k = (int)blockIdx.x;
    const int tid = (int)threadIdx.x;
    off_s[tid] = (unsigned)bbase[tid] + pc[k * 256 + tid];
    __syncthreads();
    const int md = detect_mode64((const unsigned*)ei);
    const int e0 = k * epb;
    const int e1 = min(E, e0 + epb);
    for (int e = e0 + tid; e < e1; e += 256) {
        int d = load_edge(ei, md, (long long)E + e);
        int s = load_edge(ei, md, e);
        float wv = ew[e];
        unsigned slot = atomicAdd(&off_s[d >> BSH], 1u);
        sortedE[slot] = ((unsigned long long)(unsigned)d << 33) |
                        ((unsigned long long)(unsigned)s << 16) |
                        (unsigned long long)(unsigned short)__half_as_ushort(__float2half(wv));
    }
}

// ---------------------------------------------------------------------------
// K4: per-bucket CSR build. Bucket = 512 consecutive nodes; its edges are a
// contiguous run of sortedE. LDS: fine counts + fp32 weight sums (pass 1),
// LDS scan -> cnt/dinv/row_start, pass 2 writes edata (unique rank via LDS
// atomic; order-unstable, sum-commutative => valid).
// ---------------------------------------------------------------------------
__global__ __launch_bounds__(256) void csr_build_kernel(const unsigned long long* __restrict__ sortedE,
                                                        const int* __restrict__ bbase,
                                                        const int* __restrict__ tb,
                                                        float* __restrict__ dinv,
                                                        int* __restrict__ cnt,
                                                        int* __restrict__ row_start,
                                                        unsigned* __restrict__ edata, int N) {
    __shared__ unsigned cs[512];
    __shared__ float ws[512];
    __shared__ float dv[512];
    __shared__ unsigned sc[512];
    __shared__ unsigned cur[512];
    __shared__ int red[256];
    const int b = (int)blockIdx.x;
    const int tid = (int)threadIdx.x;
    const int n0 = b << BSH;
    const int base = bbase[b];
    const int len = tb[b];

    cs[tid] = 0; cs[tid + 256] = 0;
    ws[tid] = 0.0f; ws[tid + 256] = 0.0f;
    cur[tid] = 0; cur[tid + 256] = 0;
    __syncthreads();

    for (int i = tid; i < len; i += 256) {
        unsigned long long p = sortedE[base + i];
        unsigned fine = (unsigned)(p >> 33) - (unsigned)n0;
        atomicAdd(&cs[fine], 1u);
        __half_raw hr; hr.x = (unsigned short)(p & 0xFFFFu);
        atomicAdd(&ws[fine], __half2float((__half)hr));
    }
    __syncthreads();

    // exclusive scan of cs over 512 bins (pair per thread)
    const unsigned a0 = cs[2 * tid];
    const unsigned a1 = cs[2 * tid + 1];
    const int s2 = (int)(a0 + a1);
    red[tid] = s2;
    __syncthreads();
    for (int off = 1; off < 256; off <<= 1) {
        int t = 0;
        if (tid >= off) t = red[tid - off];
        __syncthreads();
        red[tid] += t;
        __syncthreads();
    }
    const int excl2 = red[tid] - s2;
    sc[2 * tid] = (unsigned)excl2;
    sc[2 * tid + 1] = (unsigned)(excl2 + (int)a0);

#pragma unroll
    for (int q = 0; q < 2; ++q) {
        const int f = tid + q * 256;
        const int node = n0 + f;
        const float dvv = rsqrtf(1.0f + ws[f]);  // self-loop weight 1 included
        dv[f] = dvv;
        if (node < N) {
            dinv[node] = dvv;
            cnt[node] = (int)cs[f];
            row_start[node] = base + (int)sc[f];
        }
    }
    __syncthreads();

    for (int i = tid; i < len; i += 256) {
        unsigned long long p = sortedE[base + i];
        unsigned fine = (unsigned)(p >> 33) - (unsigned)n0;
        unsigned s = (unsigned)(p >> 16) & 0x1FFFFu;
        __half_raw hr; hr.x = (unsigned short)(p & 0xFFFFu);
        float wnp = __half2float((__half)hr) * dv[fine];  // ew * dinv[dst]
        unsigned r = atomicAdd(&cur[fine], 1u);
        unsigned hb = (unsigned)__half_as_ushort(__float2half(wnp)) & 0x7fffu;
        edata[base + (int)sc[fine] + (int)r] = (s << 15) | hb;
    }
}

// ---------------------------------------------------------------------------
// CSR aggregation v4 (L1 only, A/B test vs v2): one wave per node; each
// 16-lane QUARTER gathers a full 256B H row with half8 loads -> one wave-wide
// VMEM instruction covers 4 edges. Epilogue: shfl_xor(16,32) quarter-sum.
// shfl source indices masked &63 (defensive).
// ---------------------------------------------------------------------------
__global__ __launch_bounds__(256) void agg128_kernel(const __half* __restrict__ H,
                                                     const unsigned* __restrict__ edata,
                                                     const int* __restrict__ row_start,
                                                     const int* __restrict__ cnt,
                                                     const float* __restrict__ dinv,
                                                     __half* __restrict__ Y, int N) {
    const int tid = (int)threadIdx.x;
    const int wave = tid >> 6;
    const int lane = tid & 63;
    const int q = lane >> 4;    // quarter 0..3
    const int lq = lane & 15;   // lane-in-quarter: owns cols lq*8..lq*8+7
    const int i = (int)blockIdx.x * 4 + wave;
    if (i >= N) return;

    const _Float16* Hb = (const _Float16*)H + lq * 8;
    const float di = dinv[i];
    float acc[8];
    {
        half8 h = *(const half8*)(Hb + (size_t)i * 128);
        const float dii = (q == 0) ? di * di : 0.0f;  // self only once
#pragma unroll
        for (int k = 0; k < 8; ++k) acc[k] = dii * (float)h[k];
    }

    const int base = row_start[i];
    const int n = cnt[i];
    for (int off = 0; off < n; off += 64) {
        const int rem = n - off;
        unsigned ev = 0;
        if (lane < rem) ev = edata[base + off + lane];  // lanes >= rem keep 0 (safe pad)
        const int mm = min(64, rem);
        for (int j = 0; j < mm; j += 8) {
            const unsigned ea = __shfl(ev, (j + q) & 63);
            const unsigned eb = __shfl(ev, (j + 4 + q) & 63);
            const float wa = dinv[ea >> 15] * wn_of(ea);
            const float wb = dinv[eb >> 15] * wn_of(eb);
            half8 ha = *(const half8*)(Hb + (size_t)(ea >> 15) * 128);
            half8 hb = *(const half8*)(Hb + (size_t)(eb >> 15) * 128);
#pragma unroll
            for (int k = 0; k < 8; ++k) {
                acc[k] = fmaf(wa, (float)ha[k], acc[k]);
                acc[k] = fmaf(wb, (float)hb[k], acc[k]);
            }
        }
    }

#pragma unroll
    for (int k = 0; k < 8; ++k) {
        acc[k] += __shfl_xor(acc[k], 16);
        acc[k] += __shfl_xor(acc[k], 32);
    }
    if (q == 0) {
        half8 o;
#pragma unroll
        for (int k = 0; k < 8; ++k) o[k] = (_Float16)acc[k];
        *(half8*)((_Float16*)Y + (size_t)i * 128 + lq * 8) = o;
    }
}

// ---------------------------------------------------------------------------
// CSR aggregation v2 (round-6 proven; used for L2 and L3): one WAVE per node,
// shfl-broadcast edge words, 8-deep unrolled gathers.
// ---------------------------------------------------------------------------
template <int D, bool BIAS, typename TY>
__global__ __launch_bounds__(256) void agg_kernel(const __half* __restrict__ H,
                                                  const unsigned* __restrict__ edata,
                                                  const int* __restrict__ row_start,
                                                  const int* __restrict__ cnt,
                                                  const float* __restrict__ dinv,
                                                  const float* __restrict__ bias,
                                                  TY* __restrict__ Y, int N) {
    constexpr int VPT = D / 64;  // 2 (D=128) or 1 (D=64)
    const int lane = (int)threadIdx.x & 63;
    const int i = (int)blockIdx.x * 4 + ((int)threadIdx.x >> 6);
    if (i >= N) return;
    const int c0 = lane * VPT;
    const float di = dinv[i];
    const float dii = di * di;

    float acc0, acc1 = 0.0f;
    if constexpr (VPT == 2) {
        float2 h = load2(H + (size_t)i * D + c0);
        acc0 = dii * h.x;
        acc1 = dii * h.y;
    } else {
        acc0 = dii * loadS(H + (size_t)i * D + c0);
    }

    const int base = row_start[i];
    const int n = cnt[i];
    for (int off = 0; off < n; off += 64) {
        const int rem = n - off;
        unsigned ev = 0;
        if (lane < rem) ev = edata[base + off + lane];
        const int mm = min(64, rem);
        for (int j = 0; j < mm; j += 8) {
            const unsigned e0 = __shfl(ev, j),     e1 = __shfl(ev, j + 1);
            const unsigned e2 = __shfl(ev, j + 2), e3 = __shfl(ev, j + 3);
            const unsigned e4 = __shfl(ev, j + 4), e5 = __shfl(ev, j + 5);
            const unsigned e6 = __shfl(ev, j + 6), e7 = __shfl(ev, j + 7);
            const float w0 = dinv[e0 >> 15] * wn_of(e0);
            const float w1 = dinv[e1 >> 15] * wn_of(e1);
            const float w2 = dinv[e2 >> 15] * wn_of(e2);
            const float w3 = dinv[e3 >> 15] * wn_of(e3);
            const float w4 = dinv[e4 >> 15] * wn_of(e4);
            const float w5 = dinv[e5 >> 15] * wn_of(e5);
            const float w6 = dinv[e6 >> 15] * wn_of(e6);
            const float w7 = dinv[e7 >> 15] * wn_of(e7);
            if constexpr (VPT == 2) {
                float2 h0 = load2(H + (size_t)(e0 >> 15) * D + c0);
                float2 h1 = load2(H + (size_t)(e1 >> 15) * D + c0);
                float2 h2 = load2(H + (size_t)(e2 >> 15) * D + c0);
                float2 h3 = load2(H + (size_t)(e3 >> 15) * D + c0);
                float2 h4 = load2(H + (size_t)(e4 >> 15) * D + c0);
                float2 h5 = load2(H + (size_t)(e5 >> 15) * D + c0);
                float2 h6 = load2(H + (size_t)(e6 >> 15) * D + c0);
                float2 h7 = load2(H + (size_t)(e7 >> 15) * D + c0);
                acc0 = fmaf(w0, h0.x, acc0); acc1 = fmaf(w0, h0.y, acc1);
                acc0 = fmaf(w1, h1.x, acc0); acc1 = fmaf(w1, h1.y, acc1);
                acc0 = fmaf(w2, h2.x, acc0); acc1 = fmaf(w2, h2.y, acc1);
                acc0 = fmaf(w3, h3.x, acc0); acc1 = fmaf(w3, h3.y, acc1);
                acc0 = fmaf(w4, h4.x, acc0); acc1 = fmaf(w4, h4.y, acc1);
                acc0 = fmaf(w5, h5.x, acc0); acc1 = fmaf(w5, h5.y, acc1);
                acc0 = fmaf(w6, h6.x, acc0); acc1 = fmaf(w6, h6.y, acc1);
                acc0 = fmaf(w7, h7.x, acc0); acc1 = fmaf(w7, h7.y, acc1);
            } else {
                float h0 = loadS(H + (size_t)(e0 >> 15) * D + c0);
                float h1 = loadS(H + (size_t)(e1 >> 15) * D + c0);
                float h2 = loadS(H + (size_t)(e2 >> 15) * D + c0);
                float h3 = loadS(H + (size_t)(e3 >> 15) * D + c0);
                float h4 = loadS(H + (size_t)(e4 >> 15) * D + c0);
                float h5 = loadS(H + (size_t)(e5 >> 15) * D + c0);
                float h6 = loadS(H + (size_t)(e6 >> 15) * D + c0);
                float h7 = loadS(H + (size_t)(e7 >> 15) * D + c0);
                acc0 = fmaf(w0, h0, acc0);
                acc0 = fmaf(w1, h1, acc0);
                acc0 = fmaf(w2, h2, acc0);
                acc0 = fmaf(w3, h3, acc0);
                acc0 = fmaf(w4, h4, acc0);
                acc0 = fmaf(w5, h5, acc0);
                acc0 = fmaf(w6, h6, acc0);
                acc0 = fmaf(w7, h7, acc0);
            }
        }
    }

    if constexpr (VPT == 2) {
        if (BIAS) { acc0 += bias[c0]; acc1 += bias[c0 + 1]; }
        store2(Y + (size_t)i * D + c0, acc0, acc1);
    } else {
        if (BIAS) acc0 += bias[c0];
        storeS(Y + (size_t)i * D + c0, acc0);
    }
}

// ---------------------------------------------------------------------------
// GEMM dispatch wrapper; optional extra block zeroes next layer's BN stats.
// ---------------------------------------------------------------------------
template <int M, bool BN, typename TI, bool ZERO>
__global__ __launch_bounds__(256) void gemm_mfma_kernel(const TI* __restrict__ X,
                                                        const _Float16* __restrict__ WTg,
                                                        const float* __restrict__ sc,
                                                        const float* __restrict__ sh,
                                                        __half* __restrict__ Hout, int N,
                                                        float* __restrict__ gsum,
                                                        float* __restrict__ gsq, int GB) {
    __shared__ _Float16 WT[M * 136];
    if (ZERO && (int)blockIdx.x == GB) {
        if (threadIdx.x < 128) { gsum[threadIdx.x] = 0.0f; gsq[threadIdx.x] = 0.0f; }
        return;
    }
    gemm_body<M, BN, TI>(blockIdx.x, X, WTg, sc, sh, Hout, N, WT);
}

// ---------------------------------------------------------------------------
// BatchNorm statistics (fp16 Y) + fused finalize in the LAST block (ticket).
// ---------------------------------------------------------------------------
__global__ __launch_bounds__(256) void stats_kernel(const __half* __restrict__ Y,
                                                    float* __restrict__ gsum,
                                                    float* __restrict__ gsq,
                                                    unsigned* __restrict__ tk,
                                                    const float* __restrict__ gamma,
                                                    const float* __restrict__ beta,
                                                    float* __restrict__ sc,
                                                    float* __restrict__ sh, int N) {
    __shared__ float ls[256], lq[256];
    __shared__ int lastFlag;
    const int tid = (int)threadIdx.x;
    const int c = tid & 127;
    const int half_ = tid >> 7;
    float s = 0.0f, q = 0.0f;
    for (int row = (int)blockIdx.x * 2 + half_; row < N; row += 512) {
        float v = __half2float(Y[(size_t)row * 128 + c]);
        s += v;
        q = fmaf(v, v, q);
    }
    ls[tid] = s; lq[tid] = q;
    __syncthreads();
    if (tid < 128) {
        atomicAdd(&gsum[c], ls[tid] + ls[tid + 128]);
        atomicAdd(&gsq[c],  lq[tid] + lq[tid + 128]);
    }
    __syncthreads();
    if (tid == 0) {
        unsigned t = __hip_atomic_fetch_add(tk, 1u, __ATOMIC_ACQ_REL, __HIP_MEMORY_SCOPE_AGENT);
        lastFlag = (t == (unsigned)gridDim.x - 1u) ? 1 : 0;
    }
    __syncthreads();
    if (!lastFlag) return;
    if (tid < 128) {
        float gs = __hip_atomic_load(&gsum[tid], __ATOMIC_ACQUIRE, __HIP_MEMORY_SCOPE_AGENT);
        float gq = __hip_atomic_load(&gsq[tid], __ATOMIC_ACQUIRE, __HIP_MEMORY_SCOPE_AGENT);
        float inv_n = 1.0f / (float)N;
        float mean = gs * inv_n;
        float var = gq * inv_n - mean * mean;
        float scale = gamma[tid] * rsqrtf(var + BN_EPS);
        sc[tid] = scale;
        sh[tid] = beta[tid] - mean * scale;
    }
}

// ---------------------------------------------------------------------------
// Launch (11 kernels)
// ---------------------------------------------------------------------------
extern "C" void kernel_launch(void* const* d_in, const int* in_sizes, int n_in,
                              void* d_out, int out_size, void* d_ws, size_t ws_size,
                              hipStream_t stream) {
    const float* x   = (const float*)d_in[0];
    const void*  ei  = d_in[1];
    const float* ew  = (const float*)d_in[2];
    const float* W1  = (const float*)d_in[3];
    const float* W2  = (const float*)d_in[5];
    const float* W3  = (const float*)d_in[7];
    const float* b3  = (const float*)d_in[8];
    const float* g1  = (const float*)d_in[9];
    const float* be1 = (const float*)d_in[10];
    const float* g2  = (const float*)d_in[11];
    const float* be2 = (const float*)d_in[12];
    float* out = (float*)d_out;

    const int N = in_sizes[0] / 128;   // 100000 (payload packing needs N <= 2^17)
    const int E = in_sizes[2];

    char* w = (char*)d_ws;
    size_t off = 0;
    auto alloc = [&](size_t bytes) -> void* {
        void* p = w + off;
        off += (bytes + 255) & ~(size_t)255;
        return p;
    };
    unsigned* pc     = (unsigned*)alloc((size_t)KB * 256 * 4);
    int*   tb        = (int*)  alloc(256 * 4);
    int*   bbase     = (int*)  alloc(256 * 4);
    unsigned long long* sortedE = (unsigned long long*)alloc((size_t)E * 8);
    float* dinv      = (float*)alloc((size_t)N * 4);
    int*   cnt       = (int*)  alloc((size_t)N * 4);
    int*   row_start = (int*)  alloc((size_t)N * 4);
    unsigned* edata  = (unsigned*)alloc((size_t)E * 4);
    unsigned* tk     = (unsigned*)alloc(256);
    float* gsum      = (float*)alloc(128 * 4);
    float* gsq       = (float*)alloc(128 * 4);
    float* scb       = (float*)alloc(128 * 4);
    float* shb       = (float*)alloc(128 * 4);
    _Float16* WT1    = (_Float16*)alloc(128 * 128 * 2);
    _Float16* WT2    = (_Float16*)alloc(128 * 128 * 2);
    _Float16* WT3    = (_Float16*)alloc(128 * 64 * 2);
    __half* H        = (__half*)alloc((size_t)N * 128 * 2);  // gemm out / agg in
    __half* Yh       = (__half*)alloc((size_t)N * 128 * 2);  // agg out / next gemm in
    (void)ws_size; (void)n_in; (void)out_size;

    const int epb   = (E + KB - 1) / KB;            // edges per chunk block
    const int nbuck = (N + (1 << BSH) - 1) >> BSH;  // coarse buckets (<=256)
    const int gb    = (N + 63) / 64;
    const int ab    = (N + 3) / 4;

    // K1: W transposes + tickets + coarse histogram (self-detected mode)
    init_hist_kernel<<<160 + KB, 256, 0, stream>>>(ei, tk, pc, E, epb,
                                                   W1, W2, W3, WT1, WT2, WT3);
    // K2: per-bucket scans (+ last block: bucket bases, zero BN stats L1)
    scan_pc_kernel<<<nbuck, 256, 0, stream>>>(pc, tb, bbase, gsum, gsq, &tk[0], nbuck);
    // K3: bucket scatter (first, overlaps) + GEMM1
    sort_gemm1_kernel<<<KB + gb, 256, 0, stream>>>(ei, ew, pc, bbase, sortedE, E,
                                                   epb, x, WT1, H, N);
    // K4: per-bucket CSR build -> cnt, dinv, row_start, edata
    csr_build_kernel<<<nbuck, 256, 0, stream>>>(sortedE, bbase, tb, dinv, cnt, row_start,
                                                edata, N);

    // ---- L1: Yh = Ahat*H ----  (agg v4 — A/B arm)
    agg128_kernel<<<ab, 256, 0, stream>>>(H, edata, row_start, cnt, dinv, Yh, N);
    stats_kernel<<<256, 256, 0, stream>>>(Yh, gsum, gsq, &tk[1], g1, be1, scb, shb, N);

    // ---- L2: H = relu(bn(Yh))@W2 ; Yh = Ahat*H ----  (agg v2 — control arm)
    gemm_mfma_kernel<128, true, __half, true><<<gb + 1, 256, 0, stream>>>(
        Yh, WT2, scb, shb, H, N, gsum, gsq, gb);
    agg_kernel<128, false, __half><<<ab, 256, 0, stream>>>(H, edata, row_start, cnt, dinv, nullptr, Yh, N);
    stats_kernel<<<256, 256, 0, stream>>>(Yh, gsum, gsq, &tk[2], g2, be2, scb, shb, N);

    // ---- L3: H64 = relu(bn(Yh))@W3 ; out = Ahat*H64 + b3 ----
    gemm_mfma_kernel<64, true, __half, false><<<gb, 256, 0, stream>>>(
        Yh, WT3, scb, shb, H, N, nullptr, nullptr, gb);
    agg_kernel<64, true, float><<<ab, 256, 0, stream>>>(H, edata, row_start, cnt, dinv, b3, out, N);
}